// Round 4
// baseline (536.289 us; speedup 1.0000x reference)
//
#include <hip/hip_runtime.h>
#include <hip/hip_fp16.h>

#define D 48
#define W 3
#define NX 160
#define NY 160
#define NZ 160
#define NPTS (NX*NY*NZ)        // 4,096,000
#define KNBR 8
#define EPSV 1e-5f
#define NTV (159*159*159)      // 4,019,679
#define NBTV 2048              // TV blocks
#define TVROWS (159*159)
#define CPAIRS 80
#define TVSLOTS (TVROWS*CPAIRS)   // 2,022,480
#define FBLK (NBTV*3)          // fused grid: 1-in-3 blocks do TV, rest gather
#define GBLK (NBTV*2)

typedef int   vint4   __attribute__((ext_vector_type(4)));
typedef float vfloat4 __attribute__((ext_vector_type(4)));

// workspace layout (float offsets) — IDENTICAL footprint to verified r1/r3.
#define T1_OFF 0
#define T1_SZ (W*NX*D*D)              // 1,105,920 floats
#define TVP_OFF (T1_OFF + T1_SZ)      // [0]=tv accumulator, [1]=done counter
#define G3_OFF (TVP_OFF + NBTV)       // 16B aligned
// g3h: NPTS entries of 8 bytes (half4: g0,g1,g2,pad) as uint2

__device__ inline void unpack3(uint2 u, float& f0, float& f1, float& f2) {
    __half2 lo = *reinterpret_cast<__half2*>(&u.x);
    __half2 hi = *reinterpret_cast<__half2*>(&u.y);
    f0 = __low2float(lo);
    f1 = __high2float(lo);
    f2 = __low2float(hi);
}

// ---------------------------------------------------------------------------
// k1: t1[w][a][q][r] = sum_p x[a][p] * wt[w][p][q][r].  Also zeroes the
// TV accumulator/counter (workspace is re-poisoned, not zeroed, each iter).
__global__ __launch_bounds__(256) void k1(const float* __restrict__ x,
                                          const float* __restrict__ wt,
                                          float* __restrict__ t1,
                                          float* __restrict__ tvp) {
    if (blockIdx.x == 0 && blockIdx.y == 0 && blockIdx.z == 0 && threadIdx.x == 0) {
        tvp[0] = 0.f;
        reinterpret_cast<unsigned*>(tvp)[1] = 0u;
    }
    int lane = threadIdx.x & 63;
    int wv   = threadIdx.x >> 6;
    int q    = blockIdx.x * 4 + wv;
    int a0   = blockIdx.y * 16;
    int w    = blockIdx.z;
    bool act = lane < D;

    float wreg[D];
#pragma unroll
    for (int p = 0; p < D; ++p)
        wreg[p] = act ? wt[((w*D + p)*D + q)*D + lane] : 0.f;

    for (int ai = 0; ai < 16; ++ai) {
        int a = a0 + ai;
        const float4* xp = (const float4*)(x + a*D);
        float s = 0.f;
#pragma unroll
        for (int j = 0; j < D/4; ++j) {
            float4 xv = xp[j];
            s += xv.x * wreg[4*j+0];
            s += xv.y * wreg[4*j+1];
            s += xv.z * wreg[4*j+2];
            s += xv.w * wreg[4*j+3];
        }
        if (act) t1[((w*NX + a)*D + q)*D + lane] = s;
    }
}

// ---------------------------------------------------------------------------
// kbcd v3 (verified r3): fused k2+k3, register-tiled stage D.
#define BH 20
#define ZTPAD 196              // 48*4 + 4
#define RPAD 52                // D + 4
#define T1ZONE 7840            // max(t1s 7484, zt 7836) floats
__global__ __launch_bounds__(256) void kbcd(const float* __restrict__ y,
                                            const float* __restrict__ z,
                                            const float* __restrict__ t1,
                                            uint2* __restrict__ g3h) {
    __shared__ float smem[T1ZONE + BH*W*RPAD];
    float* t1s = smem;                 // phases B,C: [(q*3+w)*52 + r]
    float* zt  = smem;                 // phase D:   [h*196 + rr*4 + v]
    float* t2s = smem + T1ZONE;        // [(bh*3+w)*52 + r]
    int tid = threadIdx.x;
    int a   = blockIdx.y;
    int b0  = blockIdx.x * BH;

    // ---- stage B: t1 slice -> t1s ----
    for (int i = tid; i < W*D*D; i += 256) {
        int w = i / (D*D), rem = i - w*(D*D);
        int q = rem / D,   r   = rem - q*D;
        t1s[(q*3 + w)*RPAD + r] = t1[(size_t)(w*NX + a)*(D*D) + rem];
    }
    __syncthreads();

    // ---- stage C: t2s[bh*3+w] = sum_q y[b0+bh][q] * t1s[q][w][:] ----
    for (int i = tid; i < BH*W*(D/4); i += 256) {
        int r4 = i % (D/4);
        int t  = i / (D/4);            // t = bh*3 + w
        int w  = t % 3, bh = t / 3;
        const vfloat4* yb = (const vfloat4*)(y + (b0 + bh)*D);
        vfloat4 s = 0;
#pragma unroll
        for (int q4 = 0; q4 < D/4; ++q4) {
            vfloat4 yv = yb[q4];
#pragma unroll
            for (int u = 0; u < 4; ++u) {
                vfloat4 tv = *(const vfloat4*)(t1s + ((q4*4+u)*3 + w)*RPAD + r4*4);
                s += yv[u] * tv;
            }
        }
        *(vfloat4*)(t2s + t*RPAD + r4*4) = s;
    }
    __syncthreads();

    // ---- stage Z: z -> zt transposed ----
    for (int i = tid; i < NZ*(D/4); i += 256) {
        int c  = i / (D/4);
        int j4 = i - c*(D/4);
        vfloat4 zv = ((const vfloat4*)(z + c*D))[j4];
        float* dst = zt + (c >> 2)*ZTPAD + (c & 3);
#pragma unroll
        for (int k = 0; k < 4; ++k)
            dst[(j4*4 + k)*4] = zv[k];
    }
    __syncthreads();

    // ---- stage D: register-tiled (2bh x 3w) x (4c) GEMM ----
    for (int slot = tid; slot < 400; slot += 256) {
        int g = slot % 10;             // bh0 = 2g
        int h = slot / 10;             // c0  = 4h
        const float* t2b = t2s + (6*g)*RPAD;
        const float* ztb = zt + h*ZTPAD;
        vfloat4 acc[2][3] = {};
#pragma unroll
        for (int j = 0; j < D/4; ++j) {
            vfloat4 zr0 = *(const vfloat4*)(ztb + j*16);
            vfloat4 zr1 = *(const vfloat4*)(ztb + j*16 + 4);
            vfloat4 zr2 = *(const vfloat4*)(ztb + j*16 + 8);
            vfloat4 zr3 = *(const vfloat4*)(ztb + j*16 + 12);
#pragma unroll
            for (int u = 0; u < 6; ++u) {
                vfloat4 T = *(const vfloat4*)(t2b + u*RPAD + j*4);
                acc[u/3][u%3] += T[0]*zr0 + T[1]*zr1 + T[2]*zr2 + T[3]*zr3;
            }
        }
#pragma unroll
        for (int bl = 0; bl < 2; ++bl) {
            int b = b0 + 2*g + bl;
#pragma unroll
            for (int v = 0; v < 4; ++v) {
                int c = 4*h + v;
                __half2 lo = __halves2half2(__float2half_rn(acc[bl][0][v]),
                                            __float2half_rn(acc[bl][1][v]));
                __half2 hi = __halves2half2(__float2half_rn(acc[bl][2][v]),
                                            __float2half_rn(0.f));
                uint2 uu;
                uu.x = *reinterpret_cast<unsigned*>(&lo);
                uu.y = *reinterpret_cast<unsigned*>(&hi);
                g3h[(size_t)(a*NY + b)*NZ + c] = uu;
            }
        }
    }
}

// ---------------------------------------------------------------------------
__device__ inline float tv3(uint2 u0, uint2 uc, uint2 ub, uint2 ua) {
    float b0,b1,b2, c0,c1,c2, d0,d1,d2, e0,e1,e2;
    unpack3(u0,b0,b1,b2); unpack3(uc,c0,c1,c2);
    unpack3(ub,d0,d1,d2); unpack3(ua,e0,e1,e2);
    float x0=c0-b0, y0=d0-b0, z0=e0-b0;
    float x1=c1-b1, y1=d1-b1, z1=e1-b1;
    float x2=c2-b2, y2=d2-b2, z2=e2-b2;
    return sqrtf(EPSV + x0*x0 + y0*y0 + z0*z0)
         + sqrtf(EPSV + x1*x1 + y1*y1 + z1*z1)
         + sqrtf(EPSV + x2*x2 + y2*y2 + z2*z2);
}

// ---------------------------------------------------------------------------
// ktvg: fused TV + gather + final TV reduction (last-block pattern).
// TV blocks get an XCD-chunked slot range: with round-robin blk%8->XCD,
// tvb = (t&7)*256 + t>>3 gives each XCD a contiguous 3160-row slab, so
// b+1 / a+1 neighbor re-reads hit the SAME XCD's L2 (saves ~40 MB fills).
__global__ __launch_bounds__(256) void ktvg(const uint2* __restrict__ g3h,
                                            float* __restrict__ tvp,
                                            const int* __restrict__ bidx,
                                            const float* __restrict__ bw,
                                            float* __restrict__ out,
                                            float* __restrict__ outreg,
                                            int np) {
    int blk = blockIdx.x;
    if (blk % 3 == 2) {
        // ---- TV path ----
        int t   = blk / 3;
        int tvb = ((t & 7) << 8) + (t >> 3);   // XCD-chunked bijection
        float v = 0.f;
        for (int s = tvb * 256 + threadIdx.x; s < TVSLOTS; s += NBTV * 256) {
            int c2  = s % CPAIRS;
            int row = s / CPAIRS;
            int b   = row % 159;
            int a   = row / 159;
            int c   = 2*c2;
            size_t p = (size_t)(a*NY + b)*NZ + c;
            uint4 u0 = *(const uint4*)(g3h + p);          // points c, c+1
            uint4 ub = *(const uint4*)(g3h + p + NZ);     // b+1 neighbors
            uint4 ua = *(const uint4*)(g3h + p + NY*NZ);  // a+1 neighbors
            uint2 un = g3h[p + 2];                        // c+2 (in-bounds)
            uint2 u0l = make_uint2(u0.x, u0.y), u0h = make_uint2(u0.z, u0.w);
            uint2 ubl = make_uint2(ub.x, ub.y), ubh = make_uint2(ub.z, ub.w);
            uint2 ual = make_uint2(ua.x, ua.y), uah = make_uint2(ua.z, ua.w);
            v += tv3(u0l, u0h, ubl, ual);
            if (c + 1 < 159)
                v += tv3(u0h, un, ubh, uah);
        }
#pragma unroll
        for (int off = 32; off > 0; off >>= 1)
            v += __shfl_down(v, off, 64);
        __shared__ float sred[4];
        int lane = threadIdx.x & 63, wv = threadIdx.x >> 6;
        if (lane == 0) sred[wv] = v;
        __syncthreads();
        if (threadIdx.x == 0) {
            float vb = sred[0] + sred[1] + sred[2] + sred[3];
            atomicAdd(&tvp[0], vb);                    // device-scope, coherent
            __threadfence();
            unsigned* cnt = reinterpret_cast<unsigned*>(tvp) + 1;
            unsigned old = atomicAdd(cnt, 1u);
            if (old == NBTV - 1) {                     // last TV block done
                float total = atomicAdd(&tvp[0], 0.f); // coherent read
                outreg[0] = total * (1.0f / (float)NTV);
            }
        }
        return;
    }

    // ---- gather path ----
    int gb  = (blk / 3) * 2 + (blk % 3);
    int gid = gb * 256 + threadIdx.x;
    int half = np >> 1;
    if (gid >= half) return;
    int n1 = gid, n2 = gid + half;

    const vint4*   ip = (const vint4*)bidx;
    const vfloat4* wp = (const vfloat4*)bw;
    vint4   i0 = __builtin_nontemporal_load(ip + (size_t)n1*2);
    vint4   i1 = __builtin_nontemporal_load(ip + (size_t)n1*2 + 1);
    vint4   j0 = __builtin_nontemporal_load(ip + (size_t)n2*2);
    vint4   j1 = __builtin_nontemporal_load(ip + (size_t)n2*2 + 1);
    vfloat4 w0 = __builtin_nontemporal_load(wp + (size_t)n1*2);
    vfloat4 w1 = __builtin_nontemporal_load(wp + (size_t)n1*2 + 1);
    vfloat4 v0 = __builtin_nontemporal_load(wp + (size_t)n2*2);
    vfloat4 v1 = __builtin_nontemporal_load(wp + (size_t)n2*2 + 1);

    int   idsA[KNBR] = {i0.x, i0.y, i0.z, i0.w, i1.x, i1.y, i1.z, i1.w};
    int   idsB[KNBR] = {j0.x, j0.y, j0.z, j0.w, j1.x, j1.y, j1.z, j1.w};
    float wwsA[KNBR] = {w0.x, w0.y, w0.z, w0.w, w1.x, w1.y, w1.z, w1.w};
    float wwsB[KNBR] = {v0.x, v0.y, v0.z, v0.w, v1.x, v1.y, v1.z, v1.w};

    uint2 uA[KNBR], uB[KNBR];
#pragma unroll
    for (int k = 0; k < KNBR; ++k) uA[k] = g3h[(size_t)idsA[k]];
#pragma unroll
    for (int k = 0; k < KNBR; ++k) uB[k] = g3h[(size_t)idsB[k]];

    float a0=0.f, a1=0.f, a2=0.f, b0=0.f, b1=0.f, b2=0.f;
#pragma unroll
    for (int k = 0; k < KNBR; ++k) {
        float f0,f1,f2;
        unpack3(uA[k], f0,f1,f2);
        a0 += f0*wwsA[k]; a1 += f1*wwsA[k]; a2 += f2*wwsA[k];
    }
#pragma unroll
    for (int k = 0; k < KNBR; ++k) {
        float f0,f1,f2;
        unpack3(uB[k], f0,f1,f2);
        b0 += f0*wwsB[k]; b1 += f1*wwsB[k]; b2 += f2*wwsB[k];
    }
    float* opA = out + (size_t)n1*3;
    float* opB = out + (size_t)n2*3;
    __builtin_nontemporal_store(a0, opA+0);
    __builtin_nontemporal_store(a1, opA+1);
    __builtin_nontemporal_store(a2, opA+2);
    __builtin_nontemporal_store(b0, opB+0);
    __builtin_nontemporal_store(b1, opB+1);
    __builtin_nontemporal_store(b2, opB+2);
}

// ---------------------------------------------------------------------------
extern "C" void kernel_launch(void* const* d_in, const int* in_sizes, int n_in,
                              void* d_out, int out_size, void* d_ws, size_t ws_size,
                              hipStream_t stream) {
    const float* x    = (const float*)d_in[0];
    const float* y    = (const float*)d_in[1];
    const float* z    = (const float*)d_in[2];
    const float* wt   = (const float*)d_in[3];
    const int*   bidx = (const int*)d_in[4];
    const float* bw   = (const float*)d_in[5];
    float* out = (float*)d_out;
    float* ws  = (float*)d_ws;

    float* t1  = ws + T1_OFF;
    float* tvp = ws + TVP_OFF;
    uint2* g3h = (uint2*)(ws + G3_OFF);
    int np = in_sizes[4] / KNBR;   // 2,000,000

    k1  <<<dim3(12, 10, 3), 256, 0, stream>>>(x, wt, t1, tvp);
    kbcd<<<dim3(NY/BH, NX), 256, 0, stream>>>(y, z, t1, g3h);

    ktvg<<<dim3(FBLK), 256, 0, stream>>>(g3h, tvp, bidx, bw, out,
                                         out + (out_size - 1), np);
}

// Round 5
// 484.548 us; speedup vs baseline: 1.1068x; 1.1068x over previous
//
#include <hip/hip_runtime.h>
#include <hip/hip_fp16.h>

#define D 48
#define W 3
#define NX 160
#define NY 160
#define NZ 160
#define NPTS (NX*NY*NZ)        // 4,096,000
#define KNBR 8
#define EPSV 1e-5f
#define NTV (159*159*159)      // 4,019,679
#define NBTV 2048              // TV partial blocks
#define TVROWS (159*159)
#define CPAIRS 80
#define TVSLOTS (TVROWS*CPAIRS)   // 2,022,480
#define FBLK (NBTV*3)          // fused grid: 1-in-3 blocks do TV, rest gather
#define GBLK (NBTV*2)

typedef int   vint4   __attribute__((ext_vector_type(4)));
typedef float vfloat4 __attribute__((ext_vector_type(4)));

// workspace layout (float offsets) — IDENTICAL footprint to verified r1/r3.
#define T1_OFF 0
#define T1_SZ (W*NX*D*D)              // 1,105,920 floats
#define TVP_OFF (T1_OFF + T1_SZ)
#define G3_OFF (TVP_OFF + NBTV)       // 16B aligned
// g3h: NPTS entries of 8 bytes (half4: g0,g1,g2,pad) as uint2

__device__ inline void unpack3(uint2 u, float& f0, float& f1, float& f2) {
    __half2 lo = *reinterpret_cast<__half2*>(&u.x);
    __half2 hi = *reinterpret_cast<__half2*>(&u.y);
    f0 = __low2float(lo);
    f1 = __high2float(lo);
    f2 = __low2float(hi);
}

__device__ inline unsigned packh2(float x, float y) {
    __half2 t = __halves2half2(__float2half_rn(x), __float2half_rn(y));
    return *reinterpret_cast<unsigned*>(&t);
}

// ---------------------------------------------------------------------------
// k1: t1[w][a][q][r] = sum_p x[a][p] * wt[w][p][q][r]
__global__ __launch_bounds__(256) void k1(const float* __restrict__ x,
                                          const float* __restrict__ wt,
                                          float* __restrict__ t1) {
    int lane = threadIdx.x & 63;
    int wv   = threadIdx.x >> 6;
    int q    = blockIdx.x * 4 + wv;
    int a0   = blockIdx.y * 16;
    int w    = blockIdx.z;
    bool act = lane < D;

    float wreg[D];
#pragma unroll
    for (int p = 0; p < D; ++p)
        wreg[p] = act ? wt[((w*D + p)*D + q)*D + lane] : 0.f;

    for (int ai = 0; ai < 16; ++ai) {
        int a = a0 + ai;
        const float4* xp = (const float4*)(x + a*D);
        float s = 0.f;
#pragma unroll
        for (int j = 0; j < D/4; ++j) {
            float4 xv = xp[j];
            s += xv.x * wreg[4*j+0];
            s += xv.y * wreg[4*j+1];
            s += xv.z * wreg[4*j+2];
            s += xv.w * wreg[4*j+3];
        }
        if (act) t1[((w*NX + a)*D + q)*D + lane] = s;
    }
}

// ---------------------------------------------------------------------------
// kbcd (r3-verified structure): fused k2+k3, register-tiled stage D.
//  r5 micro-opts: stage B via float4/ds_write_b128; stage D stores packed
//  into 2x dwordx4 per (bl) instead of 8x 8B (4x fewer store instrs).
#define BH 20
#define ZTPAD 196              // 48*4 + 4
#define RPAD 52                // D + 4
#define T1ZONE 7840            // max(t1s 7484, zt 7836) floats
__global__ __launch_bounds__(256) void kbcd(const float* __restrict__ y,
                                            const float* __restrict__ z,
                                            const float* __restrict__ t1,
                                            uint2* __restrict__ g3h) {
    __shared__ float smem[T1ZONE + BH*W*RPAD];
    float* t1s = smem;                 // phases B,C: [(q*3+w)*52 + r]
    float* zt  = smem;                 // phase D:   [h*196 + rr*4 + v]
    float* t2s = smem + T1ZONE;        // [(bh*3+w)*52 + r]
    int tid = threadIdx.x;
    int a   = blockIdx.y;
    int b0  = blockIdx.x * BH;

    // ---- stage B: t1 slice -> t1s, f4 loads + b128 LDS writes ----
    // rem4 = q*(D/4)+r4: the 4 floats stay within row q -> contiguous in t1s.
    for (int i4 = tid; i4 < W*D*(D/4); i4 += 256) {
        int w    = i4 / (D*(D/4));
        int rem4 = i4 - w*(D*(D/4));
        int q    = rem4 / (D/4), r4 = rem4 - q*(D/4);
        vfloat4 v = ((const vfloat4*)(t1 + (size_t)(w*NX + a)*(D*D)))[rem4];
        *(vfloat4*)(t1s + (q*3 + w)*RPAD + r4*4) = v;
    }
    __syncthreads();

    // ---- stage C: t2s[bh*3+w] = sum_q y[b0+bh][q] * t1s[q][w][:] ----
    for (int i = tid; i < BH*W*(D/4); i += 256) {
        int r4 = i % (D/4);
        int t  = i / (D/4);            // t = bh*3 + w
        int w  = t % 3, bh = t / 3;
        const vfloat4* yb = (const vfloat4*)(y + (b0 + bh)*D);
        vfloat4 s = 0;
#pragma unroll
        for (int q4 = 0; q4 < D/4; ++q4) {
            vfloat4 yv = yb[q4];
#pragma unroll
            for (int u = 0; u < 4; ++u) {
                vfloat4 tv = *(const vfloat4*)(t1s + ((q4*4+u)*3 + w)*RPAD + r4*4);
                s += yv[u] * tv;
            }
        }
        *(vfloat4*)(t2s + t*RPAD + r4*4) = s;
    }
    __syncthreads();

    // ---- stage Z: z -> zt transposed: zt[h][rr][v] = z[4h+v][rr] ----
    for (int i = tid; i < NZ*(D/4); i += 256) {
        int c  = i / (D/4);
        int j4 = i - c*(D/4);
        vfloat4 zv = ((const vfloat4*)(z + c*D))[j4];
        float* dst = zt + (c >> 2)*ZTPAD + (c & 3);
#pragma unroll
        for (int k = 0; k < 4; ++k)
            dst[(j4*4 + k)*4] = zv[k];
    }
    __syncthreads();

    // ---- stage D: register-tiled (2bh x 3w) x (4c) GEMM ----
    for (int slot = tid; slot < 400; slot += 256) {
        int g = slot % 10;             // bh0 = 2g
        int h = slot / 10;             // c0  = 4h
        const float* t2b = t2s + (6*g)*RPAD;
        const float* ztb = zt + h*ZTPAD;
        vfloat4 acc[2][3] = {};
#pragma unroll
        for (int j = 0; j < D/4; ++j) {
            vfloat4 zr0 = *(const vfloat4*)(ztb + j*16);
            vfloat4 zr1 = *(const vfloat4*)(ztb + j*16 + 4);
            vfloat4 zr2 = *(const vfloat4*)(ztb + j*16 + 8);
            vfloat4 zr3 = *(const vfloat4*)(ztb + j*16 + 12);
#pragma unroll
            for (int u = 0; u < 6; ++u) {
                vfloat4 T = *(const vfloat4*)(t2b + u*RPAD + j*4);
                acc[u/3][u%3] += T[0]*zr0 + T[1]*zr1 + T[2]*zr2 + T[3]*zr3;
            }
        }
#pragma unroll
        for (int bl = 0; bl < 2; ++bl) {
            int b = b0 + 2*g + bl;
            // pack 4 consecutive-c points (8B each) into 2x 16B stores
            uint4 s0, s1;
            s0.x = packh2(acc[bl][0][0], acc[bl][1][0]);
            s0.y = packh2(acc[bl][2][0], 0.f);
            s0.z = packh2(acc[bl][0][1], acc[bl][1][1]);
            s0.w = packh2(acc[bl][2][1], 0.f);
            s1.x = packh2(acc[bl][0][2], acc[bl][1][2]);
            s1.y = packh2(acc[bl][2][2], 0.f);
            s1.z = packh2(acc[bl][0][3], acc[bl][1][3]);
            s1.w = packh2(acc[bl][2][3], 0.f);
            uint4* dst = (uint4*)(g3h + (size_t)(a*NY + b)*NZ + 4*h);
            dst[0] = s0;
            dst[1] = s1;
        }
    }
}

// ---------------------------------------------------------------------------
__device__ inline float tv3(uint2 u0, uint2 uc, uint2 ub, uint2 ua) {
    float b0,b1,b2, c0,c1,c2, d0,d1,d2, e0,e1,e2;
    unpack3(u0,b0,b1,b2); unpack3(uc,c0,c1,c2);
    unpack3(ub,d0,d1,d2); unpack3(ua,e0,e1,e2);
    float x0=c0-b0, y0=d0-b0, z0=e0-b0;
    float x1=c1-b1, y1=d1-b1, z1=e1-b1;
    float x2=c2-b2, y2=d2-b2, z2=e2-b2;
    return sqrtf(EPSV + x0*x0 + y0*y0 + z0*z0)
         + sqrtf(EPSV + x1*x1 + y1*y1 + z1*z1)
         + sqrtf(EPSV + x2*x2 + y2*y2 + z2*z2);
}

// ---------------------------------------------------------------------------
// ktvg (r3-verified): fused TV + gather. Identity tvb mapping — TV blocks'
// launch-order row adjacency IS the L2 locality (r4's swizzle broke it).
__global__ __launch_bounds__(256) void ktvg(const uint2* __restrict__ g3h,
                                            float* __restrict__ partial,
                                            const int* __restrict__ bidx,
                                            const float* __restrict__ bw,
                                            float* __restrict__ out,
                                            int np) {
    int blk = blockIdx.x;
    if (blk % 3 == 2) {
        // ---- TV path ----
        int tvb = blk / 3;
        float v = 0.f;
        for (int s = tvb * 256 + threadIdx.x; s < TVSLOTS; s += NBTV * 256) {
            int c2  = s % CPAIRS;
            int row = s / CPAIRS;
            int b   = row % 159;
            int a   = row / 159;
            int c   = 2*c2;
            size_t p = (size_t)(a*NY + b)*NZ + c;
            uint4 u0 = *(const uint4*)(g3h + p);          // points c, c+1
            uint4 ub = *(const uint4*)(g3h + p + NZ);     // b+1 neighbors
            uint4 ua = *(const uint4*)(g3h + p + NY*NZ);  // a+1 neighbors
            uint2 un = g3h[p + 2];                        // c+2 (in-bounds)
            uint2 u0l = make_uint2(u0.x, u0.y), u0h = make_uint2(u0.z, u0.w);
            uint2 ubl = make_uint2(ub.x, ub.y), ubh = make_uint2(ub.z, ub.w);
            uint2 ual = make_uint2(ua.x, ua.y), uah = make_uint2(ua.z, ua.w);
            v += tv3(u0l, u0h, ubl, ual);
            if (c + 1 < 159)
                v += tv3(u0h, un, ubh, uah);
        }
#pragma unroll
        for (int off = 32; off > 0; off >>= 1)
            v += __shfl_down(v, off, 64);
        __shared__ float sred[4];
        int lane = threadIdx.x & 63, wv = threadIdx.x >> 6;
        if (lane == 0) sred[wv] = v;
        __syncthreads();
        if (threadIdx.x == 0)
            partial[tvb] = sred[0] + sred[1] + sred[2] + sred[3];
        return;
    }

    // ---- gather path ----
    int gb  = (blk / 3) * 2 + (blk % 3);
    int gid = gb * 256 + threadIdx.x;
    int half = np >> 1;
    if (gid >= half) return;
    int n1 = gid, n2 = gid + half;

    const vint4*   ip = (const vint4*)bidx;
    const vfloat4* wp = (const vfloat4*)bw;
    vint4   i0 = __builtin_nontemporal_load(ip + (size_t)n1*2);
    vint4   i1 = __builtin_nontemporal_load(ip + (size_t)n1*2 + 1);
    vint4   j0 = __builtin_nontemporal_load(ip + (size_t)n2*2);
    vint4   j1 = __builtin_nontemporal_load(ip + (size_t)n2*2 + 1);
    vfloat4 w0 = __builtin_nontemporal_load(wp + (size_t)n1*2);
    vfloat4 w1 = __builtin_nontemporal_load(wp + (size_t)n1*2 + 1);
    vfloat4 v0 = __builtin_nontemporal_load(wp + (size_t)n2*2);
    vfloat4 v1 = __builtin_nontemporal_load(wp + (size_t)n2*2 + 1);

    int   idsA[KNBR] = {i0.x, i0.y, i0.z, i0.w, i1.x, i1.y, i1.z, i1.w};
    int   idsB[KNBR] = {j0.x, j0.y, j0.z, j0.w, j1.x, j1.y, j1.z, j1.w};
    float wwsA[KNBR] = {w0.x, w0.y, w0.z, w0.w, w1.x, w1.y, w1.z, w1.w};
    float wwsB[KNBR] = {v0.x, v0.y, v0.z, v0.w, v1.x, v1.y, v1.z, v1.w};

    uint2 uA[KNBR], uB[KNBR];
#pragma unroll
    for (int k = 0; k < KNBR; ++k) uA[k] = g3h[(size_t)idsA[k]];
#pragma unroll
    for (int k = 0; k < KNBR; ++k) uB[k] = g3h[(size_t)idsB[k]];

    float a0=0.f, a1=0.f, a2=0.f, b0=0.f, b1=0.f, b2=0.f;
#pragma unroll
    for (int k = 0; k < KNBR; ++k) {
        float f0,f1,f2;
        unpack3(uA[k], f0,f1,f2);
        a0 += f0*wwsA[k]; a1 += f1*wwsA[k]; a2 += f2*wwsA[k];
    }
#pragma unroll
    for (int k = 0; k < KNBR; ++k) {
        float f0,f1,f2;
        unpack3(uB[k], f0,f1,f2);
        b0 += f0*wwsB[k]; b1 += f1*wwsB[k]; b2 += f2*wwsB[k];
    }
    float* opA = out + (size_t)n1*3;
    float* opB = out + (size_t)n2*3;
    __builtin_nontemporal_store(a0, opA+0);
    __builtin_nontemporal_store(a1, opA+1);
    __builtin_nontemporal_store(a2, opA+2);
    __builtin_nontemporal_store(b0, opB+0);
    __builtin_nontemporal_store(b1, opB+1);
    __builtin_nontemporal_store(b2, opB+2);
}

__global__ __launch_bounds__(256) void kred(const float* __restrict__ partial,
                                            float* __restrict__ outreg) {
    float v = 0.f;
    for (int i = threadIdx.x; i < NBTV; i += 256) v += partial[i];
#pragma unroll
    for (int off = 32; off > 0; off >>= 1)
        v += __shfl_down(v, off, 64);
    __shared__ float sred[4];
    int lane = threadIdx.x & 63, wv = threadIdx.x >> 6;
    if (lane == 0) sred[wv] = v;
    __syncthreads();
    if (threadIdx.x == 0)
        outreg[0] = (sred[0] + sred[1] + sred[2] + sred[3]) * (1.0f / (float)NTV);
}

// ---------------------------------------------------------------------------
extern "C" void kernel_launch(void* const* d_in, const int* in_sizes, int n_in,
                              void* d_out, int out_size, void* d_ws, size_t ws_size,
                              hipStream_t stream) {
    const float* x    = (const float*)d_in[0];
    const float* y    = (const float*)d_in[1];
    const float* z    = (const float*)d_in[2];
    const float* wt   = (const float*)d_in[3];
    const int*   bidx = (const int*)d_in[4];
    const float* bw   = (const float*)d_in[5];
    float* out = (float*)d_out;
    float* ws  = (float*)d_ws;

    float* t1  = ws + T1_OFF;
    float* tvp = ws + TVP_OFF;
    uint2* g3h = (uint2*)(ws + G3_OFF);
    int np = in_sizes[4] / KNBR;   // 2,000,000

    k1  <<<dim3(12, 10, 3), 256, 0, stream>>>(x, wt, t1);
    kbcd<<<dim3(NY/BH, NX), 256, 0, stream>>>(y, z, t1, g3h);

    ktvg<<<dim3(FBLK), 256, 0, stream>>>(g3h, tvp, bidx, bw, out, np);
    kred<<<dim3(1),    256, 0, stream>>>(tvp, out + (out_size - 1));
}